// Round 1
// baseline (434.576 us; speedup 1.0000x reference)
//
#include <hip/hip_runtime.h>

// ComplexResNet fused single-pass kernel (fp32, VALU-bound).
// Strategy: 1 thread = 1 sample; full cascade streaming with 3-col register
// windows; weights pre-transformed (tanh stages scaled by 2*log2e, sigmoid
// stages by -log2e, complex-conv biases pre-combined) by a tiny prep kernel
// into d_ws. Outer schedule loop kept rolled for I$ residency.

#define ALPHA 2.8853900817779268f   /* 2*log2(e) */
#define BETA (-1.4426950408889634f) /* -log2(e) */

#if __has_builtin(__builtin_amdgcn_exp2f)
#define EXP2(x) __builtin_amdgcn_exp2f(x)
#else
#define EXP2(x) exp2f(x)
#endif
#if __has_builtin(__builtin_amdgcn_rcpf)
#define RCP(x) __builtin_amdgcn_rcpf(x)
#else
#define RCP(x) (1.0f / (x))
#endif

enum {
  OW1R = 0, OW1I = 24, OB1R = 48, OB1I = 56,
  OW2R = 64, OW2I = 256, OB2R = 448, OB2I = 456,
  OSCR = 464, OSCI = 472, OSBR = 480, OSBI = 488,
  OV1R = 496, OV1I = 592, OC1R = 688, OC1I = 692,
  OV2R = 696, OV2I = 744, OC2R = 792, OC2I = 796,
  OS2R = 800, OS2I = 832, OS2BR = 864, OS2BI = 868,
  OPR = 872, OPI = 1512, OLBR = 2152, OLBI = 2172,
  OF1 = 2192, OF1B = 2392, OF2 = 2402, OF2B = 2502,
  OF3 = 2512, OF3B = 2522, WTOT = 2523
};

__global__ void crn_prep(float* __restrict__ W,
    const float* r1c1_wr, const float* r1c1_wi, const float* r1c1_br, const float* r1c1_bi,
    const float* r1c2_wr, const float* r1c2_wi, const float* r1c2_br, const float* r1c2_bi,
    const float* r1sc_wr, const float* r1sc_wi, const float* r1sc_br, const float* r1sc_bi,
    const float* r2c1_wr, const float* r2c1_wi, const float* r2c1_br, const float* r2c1_bi,
    const float* r2c2_wr, const float* r2c2_wi, const float* r2c2_br, const float* r2c2_bi,
    const float* r2sc_wr, const float* r2sc_wi, const float* r2sc_br, const float* r2sc_bi,
    const float* la_wr, const float* la_wi, const float* la_br, const float* la_bi,
    const float* fc1_w, const float* fc1_b, const float* fc2_w, const float* fc2_b,
    const float* fc3_w, const float* fc3_b)
{
  const int t = threadIdx.x;
#define SEG(n) for (int i = t; i < (n); i += 256)
  SEG(24)  W[OW1R + i] = ALPHA * r1c1_wr[i];
  SEG(24)  W[OW1I + i] = ALPHA * r1c1_wi[i];
  SEG(8)   W[OB1R + i] = ALPHA * (r1c1_br[i] - r1c1_bi[i]);
  SEG(8)   W[OB1I + i] = ALPHA * (r1c1_br[i] + r1c1_bi[i]);
  SEG(192) W[OW2R + i] = ALPHA * r1c2_wr[i];
  SEG(192) W[OW2I + i] = ALPHA * r1c2_wi[i];
  SEG(8)   W[OB2R + i] = ALPHA * (r1c2_br[i] - r1c2_bi[i]);
  SEG(8)   W[OB2I + i] = ALPHA * (r1c2_br[i] + r1c2_bi[i]);
  SEG(8)   W[OSCR + i] = r1sc_wr[i];
  SEG(8)   W[OSCI + i] = r1sc_wi[i];
  SEG(8)   W[OSBR + i] = r1sc_br[i] - r1sc_bi[i];
  SEG(8)   W[OSBI + i] = r1sc_br[i] + r1sc_bi[i];
  SEG(96)  W[OV1R + i] = ALPHA * r2c1_wr[i];
  SEG(96)  W[OV1I + i] = ALPHA * r2c1_wi[i];
  SEG(4)   W[OC1R + i] = ALPHA * (r2c1_br[i] - r2c1_bi[i]);
  SEG(4)   W[OC1I + i] = ALPHA * (r2c1_br[i] + r2c1_bi[i]);
  SEG(48)  W[OV2R + i] = ALPHA * r2c2_wr[i];
  SEG(48)  W[OV2I + i] = ALPHA * r2c2_wi[i];
  SEG(4)   W[OC2R + i] = ALPHA * (r2c2_br[i] - r2c2_bi[i]);
  SEG(4)   W[OC2I + i] = ALPHA * (r2c2_br[i] + r2c2_bi[i]);
  SEG(32)  W[OS2R + i] = r2sc_wr[i];
  SEG(32)  W[OS2I + i] = r2sc_wi[i];
  SEG(4)   W[OS2BR + i] = r2sc_br[i] - r2sc_bi[i];
  SEG(4)   W[OS2BI + i] = r2sc_br[i] + r2sc_bi[i];
  SEG(640) { int mm = i / 20, j = i % 20; W[OPR + i] = BETA * la_wr[j * 32 + mm]; }
  SEG(640) { int mm = i / 20, j = i % 20; W[OPI + i] = BETA * la_wi[j * 32 + mm]; }
  SEG(20)  W[OLBR + i] = BETA * la_br[i];
  SEG(20)  W[OLBI + i] = BETA * la_bi[i];
  SEG(200) W[OF1 + i] = ALPHA * fc1_w[i];
  SEG(10)  W[OF1B + i] = ALPHA * fc1_b[i];
  SEG(100) W[OF2 + i] = ALPHA * fc2_w[i];
  SEG(10)  W[OF2B + i] = ALPHA * fc2_b[i];
  SEG(10)  W[OF3 + i] = fc3_w[i];
  SEG(1)   W[OF3B + i] = fc3_b[i];
#undef SEG
}

// tanh(y) where z = 2*log2(e)*y was produced by pre-scaled weights.
__device__ __forceinline__ float tanh_pre(float z) {
  float t = EXP2(z);
  float r = RCP(t + 1.0f);
  return fmaf(-2.0f, r, 1.0f);
}

// conv 1->8 k3 (+tanh), inputs are 3 complex scalars (cols l-1..l+1)
__device__ __forceinline__ void c1col(float outr[8], float outi[8],
    const float xrv[3], const float xiv[3], const float* __restrict__ W)
{
#pragma unroll
  for (int o = 0; o < 8; ++o) {
    float ar = W[OB1R + o], ai = W[OB1I + o];
#pragma unroll
    for (int k = 0; k < 3; ++k) {
      float wr = W[OW1R + o * 3 + k], wi = W[OW1I + o * 3 + k];
      ar = fmaf(xrv[k], wr, ar); ar = fmaf(xiv[k], -wi, ar);
      ai = fmaf(xrv[k], wi, ai); ai = fmaf(xiv[k], wr, ai);
    }
    outr[o] = tanh_pre(ar); outi[o] = tanh_pre(ai);
  }
}

// conv 8->8 k3 over a1 window (no activation; bias included)
__device__ __forceinline__ void c2block1(float rr[8], float ri[8],
    const float a1r[3][8], const float a1i[3][8], const float* __restrict__ W)
{
#pragma unroll
  for (int o = 0; o < 8; ++o) {
    float ar = W[OB2R + o], ai = W[OB2I + o];
#pragma unroll
    for (int c = 0; c < 8; ++c) {
#pragma unroll
      for (int k = 0; k < 3; ++k) {
        float wr = W[OW2R + (o * 8 + c) * 3 + k], wi = W[OW2I + (o * 8 + c) * 3 + k];
        float pr = a1r[k][c], pi = a1i[k][c];
        ar = fmaf(pr, wr, ar); ar = fmaf(pi, -wi, ar);
        ai = fmaf(pr, wi, ai); ai = fmaf(pi, wr, ai);
      }
    }
    rr[o] = ar; ri[o] = ai;
  }
}

__global__ __launch_bounds__(256, 2)
void crn_main(const float* __restrict__ x, const float* __restrict__ W,
              float* __restrict__ out, int B)
{
  const int s = blockIdx.x * blockDim.x + threadIdx.x;
  if (s >= B) return;
  const float* xp = x + (size_t)s * 66;

  // x window: cols 2m-1 .. 2m+2
  float xr[4], xi[4];
  xr[0] = 0.f;    xi[0] = 0.f;
  xr[1] = xp[0];  xi[1] = xp[33];
  xr[2] = xp[1];  xi[2] = xp[34];
  xr[3] = xp[2];  xi[3] = xp[35];

  float a1r[3][8], a1i[3][8];   // block1 c1 output window
  float p1r[3][8], p1i[3][8];   // pooled1 window
  float u1r[3][4], u1i[3][4];   // block2 c1 output window
  float q1r[8], q1i[8];         // res1 even-col pending (pool1)
  float q2r[4], q2i[4];         // res2 even-col pending (pool2)
  float lr[20], li[20];         // complex linear accumulators

#pragma unroll
  for (int c = 0; c < 8; ++c) {
    a1r[0][c] = a1r[1][c] = a1r[2][c] = 0.f;
    a1i[0][c] = a1i[1][c] = a1i[2][c] = 0.f;
    p1r[0][c] = p1r[1][c] = p1r[2][c] = 0.f;
    p1i[0][c] = p1i[1][c] = p1i[2][c] = 0.f;
  }
#pragma unroll
  for (int c = 0; c < 4; ++c) {
    u1r[0][c] = u1r[1][c] = u1r[2][c] = 0.f;
    u1i[0][c] = u1i[1][c] = u1i[2][c] = 0.f;
    q2r[c] = q2i[c] = 0.f;
  }
#pragma unroll
  for (int j = 0; j < 20; ++j) { lr[j] = W[OLBR + j]; li[j] = W[OLBI + j]; }
#pragma unroll
  for (int c = 0; c < 8; ++c) { q1r[c] = 0.f; q1i[c] = 0.f; }

#pragma clang loop unroll(disable)
  for (int m = 0; m <= 18; ++m) {
    // ---- STEP 1: E_A(2m) (a1 col 2m), m<=16 ----
    if (m <= 16) {
#pragma unroll
      for (int c = 0; c < 8; ++c) {
        a1r[0][c] = a1r[1][c]; a1r[1][c] = a1r[2][c];
        a1i[0][c] = a1i[1][c]; a1i[1][c] = a1i[2][c];
      }
      float xrv[3] = { xr[0], xr[1], xr[2] }, xiv[3] = { xi[0], xi[1], xi[2] };
      c1col(a1r[2], a1i[2], xrv, xiv, W);
    }
    // ---- STEP 2: E_R(2m-1) + E_P(m-1), 1<=m<=16; else zero-shift p1 ----
    if (m >= 1 && m <= 16) {
      float rr[8], ri[8];
      c2block1(rr, ri, a1r, a1i, W);
#pragma unroll
      for (int o = 0; o < 8; ++o) {
        float tr = tanh_pre(rr[o]), ti = tanh_pre(ri[o]);
        float scr = fmaf(W[OSCR + o], xr[0], W[OSBR + o]);
        scr = fmaf(W[OSCI + o], -xi[0], scr);
        float sci = fmaf(W[OSCI + o], xr[0], W[OSBI + o]);
        sci = fmaf(W[OSCR + o], xi[0], sci);
        rr[o] = tr + scr; ri[o] = ti + sci;
      }
#pragma unroll
      for (int c = 0; c < 8; ++c) {
        p1r[0][c] = p1r[1][c]; p1r[1][c] = p1r[2][c];
        p1i[0][c] = p1i[1][c]; p1i[1][c] = p1i[2][c];
        p1r[2][c] = fmaxf(q1r[c], rr[c]);
        p1i[2][c] = fmaxf(q1i[c], ri[c]);
      }
    } else if (m >= 17) {
#pragma unroll
      for (int c = 0; c < 8; ++c) {
        p1r[0][c] = p1r[1][c]; p1r[1][c] = p1r[2][c]; p1r[2][c] = 0.f;
        p1i[0][c] = p1i[1][c]; p1i[1][c] = p1i[2][c]; p1i[2][c] = 0.f;
      }
    }
    // ---- STEP 3: E_U(m-2), 2<=m<=17; at m==18 zero-shift u1 ----
    if (m >= 2 && m <= 17) {
#pragma unroll
      for (int c = 0; c < 4; ++c) {
        u1r[0][c] = u1r[1][c]; u1r[1][c] = u1r[2][c];
        u1i[0][c] = u1i[1][c]; u1i[1][c] = u1i[2][c];
      }
#pragma unroll
      for (int o = 0; o < 4; ++o) {
        float ar = W[OC1R + o], ai = W[OC1I + o];
#pragma unroll
        for (int c = 0; c < 8; ++c) {
#pragma unroll
          for (int k = 0; k < 3; ++k) {
            float wr = W[OV1R + (o * 8 + c) * 3 + k], wi = W[OV1I + (o * 8 + c) * 3 + k];
            float pr = p1r[k][c], pi = p1i[k][c];
            ar = fmaf(pr, wr, ar); ar = fmaf(pi, -wi, ar);
            ai = fmaf(pr, wi, ai); ai = fmaf(pi, wr, ai);
          }
        }
        u1r[2][o] = tanh_pre(ar); u1i[2][o] = tanh_pre(ai);
      }
    } else if (m == 18) {
#pragma unroll
      for (int c = 0; c < 4; ++c) {
        u1r[0][c] = u1r[1][c]; u1r[1][c] = u1r[2][c]; u1r[2][c] = 0.f;
        u1i[0][c] = u1i[1][c]; u1i[1][c] = u1i[2][c]; u1i[2][c] = 0.f;
      }
    }
    // ---- STEP 4: E_S(m-3) + pool2/E_Q, m>=3 ----
    if (m >= 3) {
      float rr[4], ri[4];
#pragma unroll
      for (int o = 0; o < 4; ++o) {
        float ar = W[OC2R + o], ai = W[OC2I + o];
#pragma unroll
        for (int c = 0; c < 4; ++c) {
#pragma unroll
          for (int k = 0; k < 3; ++k) {
            float wr = W[OV2R + (o * 4 + c) * 3 + k], wi = W[OV2I + (o * 4 + c) * 3 + k];
            float pr = u1r[k][c], pi = u1i[k][c];
            ar = fmaf(pr, wr, ar); ar = fmaf(pi, -wi, ar);
            ai = fmaf(pr, wi, ai); ai = fmaf(pi, wr, ai);
          }
        }
        float tr = tanh_pre(ar), ti = tanh_pre(ai);
        float scr = W[OS2BR + o], sci = W[OS2BI + o];
#pragma unroll
        for (int c = 0; c < 8; ++c) {
          float wr = W[OS2R + o * 8 + c], wi = W[OS2I + o * 8 + c];
          float pr = p1r[0][c], pi = p1i[0][c];   // p1 col (m-3): shortcut input
          scr = fmaf(pr, wr, scr); scr = fmaf(pi, -wi, scr);
          sci = fmaf(pr, wi, sci); sci = fmaf(pi, wr, sci);
        }
        rr[o] = tr + scr; ri[o] = ti + sci;
      }
      if ((m & 1) == 1) {       // s = m-3 even: stash for pool2
#pragma unroll
        for (int o = 0; o < 4; ++o) { q2r[o] = rr[o]; q2i[o] = ri[o]; }
      } else {                  // s odd: emit pooled2 col q, accumulate linear
        const int q = (m - 4) >> 1;
#pragma unroll
        for (int o = 0; o < 4; ++o) {
          float pr = fmaxf(q2r[o], rr[o]), pi = fmaxf(q2i[o], ri[o]);
          const int row = o * 8 + q;
#pragma unroll
          for (int j = 0; j < 20; ++j) {
            float wr = W[OPR + row * 20 + j], wi = W[OPI + row * 20 + j];
            lr[j] = fmaf(pr, wr, lr[j]); lr[j] = fmaf(pi, -wi, lr[j]);
            li[j] = fmaf(pr, wi, li[j]); li[j] = fmaf(pi, wr, li[j]);
          }
        }
      }
    }
    // ---- STEPS 5-7: E_A(2m+1), E_R(2m)->q1, x shift + prefetch, m<=15 ----
    if (m <= 15) {
      {
#pragma unroll
        for (int c = 0; c < 8; ++c) {
          a1r[0][c] = a1r[1][c]; a1r[1][c] = a1r[2][c];
          a1i[0][c] = a1i[1][c]; a1i[1][c] = a1i[2][c];
        }
        float xrv[3] = { xr[1], xr[2], xr[3] }, xiv[3] = { xi[1], xi[2], xi[3] };
        c1col(a1r[2], a1i[2], xrv, xiv, W);
      }
      {
        float rr[8], ri[8];
        c2block1(rr, ri, a1r, a1i, W);
#pragma unroll
        for (int o = 0; o < 8; ++o) {
          float tr = tanh_pre(rr[o]), ti = tanh_pre(ri[o]);
          float scr = fmaf(W[OSCR + o], xr[1], W[OSBR + o]);
          scr = fmaf(W[OSCI + o], -xi[1], scr);
          float sci = fmaf(W[OSCI + o], xr[1], W[OSBI + o]);
          sci = fmaf(W[OSCR + o], xi[1], sci);
          q1r[o] = tr + scr; q1i[o] = ti + sci;
        }
      }
      // slide x window to cols [2m+1 .. 2m+4]
      xr[0] = xr[2]; xr[1] = xr[3]; xi[0] = xi[2]; xi[1] = xi[3];
      const int ca = 2 * m + 3, cb = 2 * m + 4;
      float nr0 = 0.f, ni0 = 0.f, nr1 = 0.f, ni1 = 0.f;
      if (ca <= 32) { nr0 = xp[ca]; ni0 = xp[33 + ca]; }
      if (cb <= 32) { nr1 = xp[cb]; ni1 = xp[33 + cb]; }
      xr[2] = nr0; xi[2] = ni0; xr[3] = nr1; xi[3] = ni1;
    }
  }

  // ---- head: sigmoid ratio -> arctan -> MLP ----
  float rho[20];
#pragma unroll
  for (int j = 0; j < 20; ++j) {
    float u = 1.0f + EXP2(lr[j]);   // = 1 + e^{-lr_true}
    float v = 1.0f + EXP2(li[j]);   // = 1 + e^{-li_true}
    // sigmoid(li)/sigmoid(lr) = u/v
    float mn = fminf(u, v), mx = fmaxf(u, v);
    float t = mn * RCP(mx);
    float z2 = t * t;
    float p = fmaf(z2, 0.0208351f, -0.0851330f);
    p = fmaf(z2, p, 0.1801410f);
    p = fmaf(z2, p, -0.3302995f);
    p = fmaf(z2, p, 0.9998660f);
    p = p * t;
    rho[j] = (u > v) ? (1.57079632679489662f - p) : p;
  }
  float h1[10];
#pragma unroll
  for (int n = 0; n < 10; ++n) {
    float z = W[OF1B + n];
#pragma unroll
    for (int j = 0; j < 20; ++j) z = fmaf(rho[j], W[OF1 + n * 20 + j], z);
    h1[n] = tanh_pre(z);
  }
  float h2[10];
#pragma unroll
  for (int n = 0; n < 10; ++n) {
    float z = W[OF2B + n];
#pragma unroll
    for (int j = 0; j < 10; ++j) z = fmaf(h1[j], W[OF2 + n * 10 + j], z);
    h2[n] = tanh_pre(z);
  }
  float o = W[OF3B];
#pragma unroll
  for (int n = 0; n < 10; ++n) o = fmaf(h2[n], W[OF3 + n], o);
  out[s] = o;
}

extern "C" void kernel_launch(void* const* d_in, const int* in_sizes, int n_in,
                              void* d_out, int out_size, void* d_ws, size_t ws_size,
                              hipStream_t stream)
{
  const float* x = (const float*)d_in[0];
  float* W = (float*)d_ws;
  crn_prep<<<1, 256, 0, stream>>>(W,
      (const float*)d_in[1],  (const float*)d_in[2],  (const float*)d_in[3],  (const float*)d_in[4],
      (const float*)d_in[5],  (const float*)d_in[6],  (const float*)d_in[7],  (const float*)d_in[8],
      (const float*)d_in[9],  (const float*)d_in[10], (const float*)d_in[11], (const float*)d_in[12],
      (const float*)d_in[13], (const float*)d_in[14], (const float*)d_in[15], (const float*)d_in[16],
      (const float*)d_in[17], (const float*)d_in[18], (const float*)d_in[19], (const float*)d_in[20],
      (const float*)d_in[21], (const float*)d_in[22], (const float*)d_in[23], (const float*)d_in[24],
      (const float*)d_in[25], (const float*)d_in[26], (const float*)d_in[27], (const float*)d_in[28],
      (const float*)d_in[29], (const float*)d_in[30], (const float*)d_in[31], (const float*)d_in[32],
      (const float*)d_in[33], (const float*)d_in[34]);
  const int B = in_sizes[0] / 66;
  const int grid = (B + 255) / 256;
  crn_main<<<grid, 256, 0, stream>>>(x, W, (float*)d_out, B);
}

// Round 3
// 320.533 us; speedup vs baseline: 1.3558x; 1.3558x over previous
//
#include <hip/hip_runtime.h>

// ComplexResNet fused single-pass kernel, round 2b: packed-f16 complex values
// + v_dot2_f32_f16 (halves MAC instruction count, halves register state).
// Accumulation stays f32; tanh/sigmoid/arctan/head stay f32.
// (Round-2 compile fix: h16 must be __fp16 to match amdgcn builtin types.)

#define ALPHA 2.8853900817779268f   /* 2*log2(e) */
#define BETA (-1.4426950408889634f) /* -log2(e) */

#if __has_builtin(__builtin_amdgcn_exp2f)
#define EXP2(x) __builtin_amdgcn_exp2f(x)
#else
#define EXP2(x) exp2f(x)
#endif
#if __has_builtin(__builtin_amdgcn_rcpf)
#define RCP(x) __builtin_amdgcn_rcpf(x)
#else
#define RCP(x) (1.0f / (x))
#endif

typedef __fp16 h16;
typedef __fp16 h16x2 __attribute__((ext_vector_type(2)));

__device__ __forceinline__ float cdot(h16x2 a, h16x2 b, float c) {
#if __has_builtin(__builtin_amdgcn_fdot2)
  return __builtin_amdgcn_fdot2(a, b, c, false);
#else
  return fmaf((float)a.x, (float)b.x, fmaf((float)a.y, (float)b.y, c));
#endif
}
__device__ __forceinline__ h16x2 pk2(float lo, float hi) {
#if __has_builtin(__builtin_amdgcn_cvt_pkrtz)
  return __builtin_amdgcn_cvt_pkrtz(lo, hi);
#else
  h16x2 r; r.x = (h16)lo; r.y = (h16)hi; return r;
#endif
}
__device__ __forceinline__ h16x2 max2(h16x2 a, h16x2 b) {
  h16x2 r;
  r.x = a.x > b.x ? a.x : b.x;
  r.y = a.y > b.y ? a.y : b.y;
  return r;
}

// dword-offset layout inside d_ws.
// Packed regions hold half2 pairs: [..*2] = (wr,-wi), [..*2+1] = (wi,wr).
enum {
  PW1 = 0,      PB1R = 48,   PB1I = 56,
  PW2 = 64,     PB2R = 448,  PB2I = 456,
  PSC = 464,    PSB1R = 480, PSB1I = 488,
  PV1 = 496,    PC1R = 688,  PC1I = 692,
  PV2 = 696,    PC2R = 792,  PC2I = 796,
  PS2 = 800,    PS2BR = 864, PS2BI = 868,
  PP = 872,     PLBR = 2152, PLBI = 2172,
  PF1 = 2192,   PF1B = 2392, PF2 = 2402,  PF2B = 2502,
  PF3 = 2512,   PF3B = 2522, WTOT = 2523
};

__device__ __forceinline__ unsigned pkw(float re, float im) {
  h16x2 h; h.x = (h16)re; h.y = (h16)im;   // RTN conversions
  return __builtin_bit_cast(unsigned, h);
}

__global__ void crn_prep(float* __restrict__ W,
    const float* r1c1_wr, const float* r1c1_wi, const float* r1c1_br, const float* r1c1_bi,
    const float* r1c2_wr, const float* r1c2_wi, const float* r1c2_br, const float* r1c2_bi,
    const float* r1sc_wr, const float* r1sc_wi, const float* r1sc_br, const float* r1sc_bi,
    const float* r2c1_wr, const float* r2c1_wi, const float* r2c1_br, const float* r2c1_bi,
    const float* r2c2_wr, const float* r2c2_wi, const float* r2c2_br, const float* r2c2_bi,
    const float* r2sc_wr, const float* r2sc_wi, const float* r2sc_br, const float* r2sc_bi,
    const float* la_wr, const float* la_wi, const float* la_br, const float* la_bi,
    const float* fc1_w, const float* fc1_b, const float* fc2_w, const float* fc2_b,
    const float* fc3_w, const float* fc3_b)
{
  const int t = threadIdx.x;
  unsigned* U = (unsigned*)W;
#define SEG(n) for (int i = t; i < (n); i += 256)
  SEG(24) { float wr = ALPHA * r1c1_wr[i], wi = ALPHA * r1c1_wi[i];
            U[PW1 + i*2] = pkw(wr, -wi); U[PW1 + i*2 + 1] = pkw(wi, wr); }
  SEG(8)   W[PB1R + i] = ALPHA * (r1c1_br[i] - r1c1_bi[i]);
  SEG(8)   W[PB1I + i] = ALPHA * (r1c1_br[i] + r1c1_bi[i]);
  SEG(192) { float wr = ALPHA * r1c2_wr[i], wi = ALPHA * r1c2_wi[i];
             U[PW2 + i*2] = pkw(wr, -wi); U[PW2 + i*2 + 1] = pkw(wi, wr); }
  SEG(8)   W[PB2R + i] = ALPHA * (r1c2_br[i] - r1c2_bi[i]);
  SEG(8)   W[PB2I + i] = ALPHA * (r1c2_br[i] + r1c2_bi[i]);
  SEG(8)  { float wr = r1sc_wr[i], wi = r1sc_wi[i];
            U[PSC + i*2] = pkw(wr, -wi); U[PSC + i*2 + 1] = pkw(wi, wr); }
  SEG(8)   W[PSB1R + i] = r1sc_br[i] - r1sc_bi[i];
  SEG(8)   W[PSB1I + i] = r1sc_br[i] + r1sc_bi[i];
  SEG(96) { float wr = ALPHA * r2c1_wr[i], wi = ALPHA * r2c1_wi[i];
            U[PV1 + i*2] = pkw(wr, -wi); U[PV1 + i*2 + 1] = pkw(wi, wr); }
  SEG(4)   W[PC1R + i] = ALPHA * (r2c1_br[i] - r2c1_bi[i]);
  SEG(4)   W[PC1I + i] = ALPHA * (r2c1_br[i] + r2c1_bi[i]);
  SEG(48) { float wr = ALPHA * r2c2_wr[i], wi = ALPHA * r2c2_wi[i];
            U[PV2 + i*2] = pkw(wr, -wi); U[PV2 + i*2 + 1] = pkw(wi, wr); }
  SEG(4)   W[PC2R + i] = ALPHA * (r2c2_br[i] - r2c2_bi[i]);
  SEG(4)   W[PC2I + i] = ALPHA * (r2c2_br[i] + r2c2_bi[i]);
  SEG(32) { float wr = r2sc_wr[i], wi = r2sc_wi[i];
            U[PS2 + i*2] = pkw(wr, -wi); U[PS2 + i*2 + 1] = pkw(wi, wr); }
  SEG(4)   W[PS2BR + i] = r2sc_br[i] - r2sc_bi[i];
  SEG(4)   W[PS2BI + i] = r2sc_br[i] + r2sc_bi[i];
  SEG(640) { int row = i / 20, j = i % 20;
             float wr = BETA * la_wr[j * 32 + row], wi = BETA * la_wi[j * 32 + row];
             U[PP + i*2] = pkw(wr, -wi); U[PP + i*2 + 1] = pkw(wi, wr); }
  SEG(20)  W[PLBR + i] = BETA * la_br[i];
  SEG(20)  W[PLBI + i] = BETA * la_bi[i];
  SEG(200) W[PF1 + i] = ALPHA * fc1_w[i];
  SEG(10)  W[PF1B + i] = ALPHA * fc1_b[i];
  SEG(100) W[PF2 + i] = ALPHA * fc2_w[i];
  SEG(10)  W[PF2B + i] = ALPHA * fc2_b[i];
  SEG(10)  W[PF3 + i] = fc3_w[i];
  SEG(1)   W[PF3B + i] = fc3_b[i];
#undef SEG
}

// tanh(y) where z = 2*log2(e)*y was produced by pre-scaled weights.
__device__ __forceinline__ float tanh_pre(float z) {
  float t = EXP2(z);
  float r = RCP(t + 1.0f);
  return fmaf(-2.0f, r, 1.0f);
}

__global__ __launch_bounds__(256, 2)
void crn_main(const float* __restrict__ x, const float* __restrict__ W,
              float* __restrict__ out, int B)
{
  const int s = blockIdx.x * blockDim.x + threadIdx.x;
  if (s >= B) return;
  const float* xp = x + (size_t)s * 66;
  const unsigned* Wu = (const unsigned*)W;
#define H2(idx) __builtin_bit_cast(h16x2, Wu[(idx)])

  // x window: cols 2m-1 .. 2m+2, packed (re,im)
  h16x2 xw[4];
  xw[0] = pk2(0.f, 0.f);
  xw[1] = pk2(xp[0], xp[33]);
  xw[2] = pk2(xp[1], xp[34]);
  xw[3] = pk2(xp[2], xp[35]);

  h16x2 a1[3][8];   // block1 c1 output window
  h16x2 p1[3][8];   // pooled1 window
  h16x2 u1[3][4];   // block2 c1 output window
  h16x2 q1[8];      // res1 even-col pending (pool1)
  h16x2 q2[4];      // res2 even-col pending (pool2)
  float lr[20], li[20];

  const h16x2 z2 = pk2(0.f, 0.f);
#pragma unroll
  for (int c = 0; c < 8; ++c) {
    a1[0][c] = a1[1][c] = a1[2][c] = z2;
    p1[0][c] = p1[1][c] = p1[2][c] = z2;
    q1[c] = z2;
  }
#pragma unroll
  for (int c = 0; c < 4; ++c) {
    u1[0][c] = u1[1][c] = u1[2][c] = z2;
    q2[c] = z2;
  }
#pragma unroll
  for (int j = 0; j < 20; ++j) { lr[j] = W[PLBR + j]; li[j] = W[PLBI + j]; }

#pragma clang loop unroll(disable)
  for (int m = 0; m <= 18; ++m) {
    // ---- STEP 1: E_A(2m) (a1 col 2m), m<=16 ----
    if (m <= 16) {
#pragma unroll
      for (int c = 0; c < 8; ++c) { a1[0][c] = a1[1][c]; a1[1][c] = a1[2][c]; }
#pragma unroll
      for (int o = 0; o < 8; ++o) {
        float ar = W[PB1R + o], ai = W[PB1I + o];
#pragma unroll
        for (int k = 0; k < 3; ++k) {
          ar = cdot(xw[k], H2(PW1 + (o*3+k)*2), ar);
          ai = cdot(xw[k], H2(PW1 + (o*3+k)*2 + 1), ai);
        }
        a1[2][o] = pk2(tanh_pre(ar), tanh_pre(ai));
      }
    }
    // ---- STEP 2: E_R(2m-1) + E_P(m-1), 1<=m<=16; else zero-shift p1 ----
    if (m >= 1 && m <= 16) {
#pragma unroll
      for (int c = 0; c < 8; ++c) { p1[0][c] = p1[1][c]; p1[1][c] = p1[2][c]; }
#pragma unroll
      for (int o = 0; o < 8; ++o) {
        float ar = W[PB2R + o], ai = W[PB2I + o];
#pragma unroll
        for (int c = 0; c < 8; ++c)
#pragma unroll
          for (int k = 0; k < 3; ++k) {
            const int idx = PW2 + ((o*8+c)*3+k)*2;
            ar = cdot(a1[k][c], H2(idx), ar);
            ai = cdot(a1[k][c], H2(idx+1), ai);
          }
        float scr = cdot(xw[0], H2(PSC + o*2),     W[PSB1R + o]);
        float sci = cdot(xw[0], H2(PSC + o*2 + 1), W[PSB1I + o]);
        h16x2 v = pk2(tanh_pre(ar) + scr, tanh_pre(ai) + sci);
        p1[2][o] = max2(q1[o], v);
      }
    } else if (m >= 17) {
#pragma unroll
      for (int c = 0; c < 8; ++c) {
        p1[0][c] = p1[1][c]; p1[1][c] = p1[2][c]; p1[2][c] = z2;
      }
    }
    // ---- STEP 3: E_U(m-2), 2<=m<=17; at m==18 zero-shift u1 ----
    if (m >= 2 && m <= 17) {
#pragma unroll
      for (int c = 0; c < 4; ++c) { u1[0][c] = u1[1][c]; u1[1][c] = u1[2][c]; }
#pragma unroll
      for (int o = 0; o < 4; ++o) {
        float ar = W[PC1R + o], ai = W[PC1I + o];
#pragma unroll
        for (int c = 0; c < 8; ++c)
#pragma unroll
          for (int k = 0; k < 3; ++k) {
            const int idx = PV1 + ((o*8+c)*3+k)*2;
            ar = cdot(p1[k][c], H2(idx), ar);
            ai = cdot(p1[k][c], H2(idx+1), ai);
          }
        u1[2][o] = pk2(tanh_pre(ar), tanh_pre(ai));
      }
    } else if (m == 18) {
#pragma unroll
      for (int c = 0; c < 4; ++c) {
        u1[0][c] = u1[1][c]; u1[1][c] = u1[2][c]; u1[2][c] = z2;
      }
    }
    // ---- STEP 4: E_S(m-3) + pool2/linear, m>=3 ----
    if (m >= 3) {
      h16x2 rv[4];
#pragma unroll
      for (int o = 0; o < 4; ++o) {
        float ar = W[PC2R + o], ai = W[PC2I + o];
#pragma unroll
        for (int c = 0; c < 4; ++c)
#pragma unroll
          for (int k = 0; k < 3; ++k) {
            const int idx = PV2 + ((o*4+c)*3+k)*2;
            ar = cdot(u1[k][c], H2(idx), ar);
            ai = cdot(u1[k][c], H2(idx+1), ai);
          }
        float scr = W[PS2BR + o], sci = W[PS2BI + o];
#pragma unroll
        for (int c = 0; c < 8; ++c) {
          const int idx = PS2 + (o*8+c)*2;
          scr = cdot(p1[0][c], H2(idx), scr);      // p1 col (m-3)
          sci = cdot(p1[0][c], H2(idx+1), sci);
        }
        rv[o] = pk2(tanh_pre(ar) + scr, tanh_pre(ai) + sci);
      }
      if ((m & 1) == 1) {       // s = m-3 even: stash for pool2
#pragma unroll
        for (int o = 0; o < 4; ++o) q2[o] = rv[o];
      } else {                  // s odd: emit pooled2 col q, accumulate linear
        const int q = (m - 4) >> 1;
#pragma unroll
        for (int o = 0; o < 4; ++o) {
          h16x2 pkd = max2(q2[o], rv[o]);
          const int row = o * 8 + q;
#pragma unroll
          for (int j = 0; j < 20; ++j) {
            lr[j] = cdot(pkd, H2(PP + (row*20+j)*2),     lr[j]);
            li[j] = cdot(pkd, H2(PP + (row*20+j)*2 + 1), li[j]);
          }
        }
      }
    }
    // ---- STEPS 5-7: E_A(2m+1), E_R(2m)->q1, x slide, m<=15 ----
    if (m <= 15) {
#pragma unroll
      for (int c = 0; c < 8; ++c) { a1[0][c] = a1[1][c]; a1[1][c] = a1[2][c]; }
#pragma unroll
      for (int o = 0; o < 8; ++o) {
        float ar = W[PB1R + o], ai = W[PB1I + o];
#pragma unroll
        for (int k = 0; k < 3; ++k) {
          ar = cdot(xw[k + 1], H2(PW1 + (o*3+k)*2), ar);
          ai = cdot(xw[k + 1], H2(PW1 + (o*3+k)*2 + 1), ai);
        }
        a1[2][o] = pk2(tanh_pre(ar), tanh_pre(ai));
      }
#pragma unroll
      for (int o = 0; o < 8; ++o) {
        float ar = W[PB2R + o], ai = W[PB2I + o];
#pragma unroll
        for (int c = 0; c < 8; ++c)
#pragma unroll
          for (int k = 0; k < 3; ++k) {
            const int idx = PW2 + ((o*8+c)*3+k)*2;
            ar = cdot(a1[k][c], H2(idx), ar);
            ai = cdot(a1[k][c], H2(idx+1), ai);
          }
        float scr = cdot(xw[1], H2(PSC + o*2),     W[PSB1R + o]);
        float sci = cdot(xw[1], H2(PSC + o*2 + 1), W[PSB1I + o]);
        q1[o] = pk2(tanh_pre(ar) + scr, tanh_pre(ai) + sci);
      }
      // slide x window to cols [2m+1 .. 2m+4]
      xw[0] = xw[2]; xw[1] = xw[3];
      const int ca = 2 * m + 3, cb = 2 * m + 4;
      float nr0 = 0.f, ni0 = 0.f, nr1 = 0.f, ni1 = 0.f;
      if (ca <= 32) { nr0 = xp[ca]; ni0 = xp[33 + ca]; }
      if (cb <= 32) { nr1 = xp[cb]; ni1 = xp[33 + cb]; }
      xw[2] = pk2(nr0, ni0); xw[3] = pk2(nr1, ni1);
    }
  }

  // ---- head: sigmoid ratio -> arctan -> MLP (f32) ----
  float rho[20];
#pragma unroll
  for (int j = 0; j < 20; ++j) {
    float u = 1.0f + EXP2(lr[j]);   // = 1 + e^{-lr_true}
    float v = 1.0f + EXP2(li[j]);   // = 1 + e^{-li_true}
    float mn = fminf(u, v), mx = fmaxf(u, v);
    float t = mn * RCP(mx);
    float zz = t * t;
    float p = fmaf(zz, 0.0208351f, -0.0851330f);
    p = fmaf(zz, p, 0.1801410f);
    p = fmaf(zz, p, -0.3302995f);
    p = fmaf(zz, p, 0.9998660f);
    p = p * t;
    rho[j] = (u > v) ? (1.57079632679489662f - p) : p;
  }
  float h1[10];
#pragma unroll
  for (int n = 0; n < 10; ++n) {
    float z = W[PF1B + n];
#pragma unroll
    for (int j = 0; j < 20; ++j) z = fmaf(rho[j], W[PF1 + n * 20 + j], z);
    h1[n] = tanh_pre(z);
  }
  float h2[10];
#pragma unroll
  for (int n = 0; n < 10; ++n) {
    float z = W[PF2B + n];
#pragma unroll
    for (int j = 0; j < 10; ++j) z = fmaf(h1[j], W[PF2 + n * 10 + j], z);
    h2[n] = tanh_pre(z);
  }
  float o = W[PF3B];
#pragma unroll
  for (int n = 0; n < 10; ++n) o = fmaf(h2[n], W[PF3 + n], o);
  out[s] = o;
#undef H2
}

extern "C" void kernel_launch(void* const* d_in, const int* in_sizes, int n_in,
                              void* d_out, int out_size, void* d_ws, size_t ws_size,
                              hipStream_t stream)
{
  const float* x = (const float*)d_in[0];
  float* W = (float*)d_ws;
  crn_prep<<<1, 256, 0, stream>>>(W,
      (const float*)d_in[1],  (const float*)d_in[2],  (const float*)d_in[3],  (const float*)d_in[4],
      (const float*)d_in[5],  (const float*)d_in[6],  (const float*)d_in[7],  (const float*)d_in[8],
      (const float*)d_in[9],  (const float*)d_in[10], (const float*)d_in[11], (const float*)d_in[12],
      (const float*)d_in[13], (const float*)d_in[14], (const float*)d_in[15], (const float*)d_in[16],
      (const float*)d_in[17], (const float*)d_in[18], (const float*)d_in[19], (const float*)d_in[20],
      (const float*)d_in[21], (const float*)d_in[22], (const float*)d_in[23], (const float*)d_in[24],
      (const float*)d_in[25], (const float*)d_in[26], (const float*)d_in[27], (const float*)d_in[28],
      (const float*)d_in[29], (const float*)d_in[30], (const float*)d_in[31], (const float*)d_in[32],
      (const float*)d_in[33], (const float*)d_in[34]);
  const int B = in_sizes[0] / 66;
  const int grid = (B + 255) / 256;
  crn_main<<<grid, 256, 0, stream>>>(x, W, (float*)d_out, B);
}